// Round 5
// baseline (316.175 us; speedup 1.0000x reference)
//
#include <hip/hip_runtime.h>

// CRF negative mean log-likelihood, B=64, T=512, U=256.
//
// Round 5: push TLP to 4 waves/SIMD (1024 thr, 16 waves, 1 n-tile/wave).
// Evidence: step time is stall-dominated (r3: 1 wave/SIMD=1300cy, r4: 2
// waves/SIMD=1045cy; busy time only ~320cy/SIMD). Broadcast ds_reads are
// cheap (r3 falsified LDS-pipe theory). Keep r4's deferred stale rescale
// (no second barrier) + CC2 normalizer + clamp-free prefetch.

#define Bc 64
#define Tc 512
#define Uc 256
#define NW 16                  // waves per block
#define LOG2E 1.4426950408889634f
#define LN2   0.6931471805599453f
#define CC2   7.2134752f       // per-step normalizer in log2 domain (= 5 nats)

typedef __bf16 bf16x8 __attribute__((ext_vector_type(8)));
typedef float  f32x4  __attribute__((ext_vector_type(4)));

// Raw barrier: does NOT drain vmcnt (pot prefetches stay in flight).
__device__ __forceinline__ void wg_barrier() {
    asm volatile("s_waitcnt lgkmcnt(0)" ::: "memory");
    __builtin_amdgcn_s_barrier();
    asm volatile("" ::: "memory");
}

__global__ __launch_bounds__(1024, 1)
void crf_fwd(const float* __restrict__ pot, const int* __restrict__ tags,
             const int* __restrict__ seqlen, const float* __restrict__ trans,
             float* __restrict__ ws, float* __restrict__ out)
{
    const int b    = blockIdx.x;
    const int tid  = threadIdx.x;          // 0..1023
    const int lane = tid & 63;
    const int w    = tid >> 6;             // wave 0..15
    const int g4   = lane >> 4;            // k-group 0..3
    const int c16  = lane & 15;            // fragment column
    const int L    = seqlen[b];

    __shared__ __align__(16) __bf16 ea_lds[2][Uc];
    __shared__ __align__(16) float mx[2][NW];  // double-buffered wave maxes
    __shared__ float wred[NW];
    __shared__ float redU[NW], redB[NW];

    const float* potb = pot  + (size_t)b * Tc * Uc;
    const int*   tagb = tags + b * Tc;

    // ---- B fragments: E = exp(trans), bf16, registers ----
    // wave w owns ONE n-tile: u in [16w, 16w+16).
    // elem e of lane l = E[v = 32kt + 8g4 + e][u = 16w + c16].
    // Same (lane,e)->k placement as A fragments (k-permutation cancels;
    // validated absmax 0.0 in rounds 1/3/4).
    bf16x8 bfr[8];
    #pragma unroll
    for (int kt = 0; kt < 8; ++kt) {
        const int u = 16 * w + c16;
        bf16x8 bb;
        #pragma unroll
        for (int e = 0; e < 8; ++e) {
            const int v = 32 * kt + 8 * g4 + e;
            bb[e] = (__bf16)__builtin_exp2f(trans[v * Uc + u] * LOG2E);
        }
        bfr[kt] = bb;
    }

    // ---- prologue: unary + binary scores, block-parallel over t ----
    {
        const int t  = tid;                // 0..1023; only t < L contribute
        float up = 0.f, bp = 0.f;
        if (t < L) {
            const int tg = tagb[t];
            up = potb[(size_t)t * Uc + tg];
            if (t >= 1) bp = trans[tagb[t - 1] * Uc + tg];
        }
        #pragma unroll
        for (int m = 1; m < 64; m <<= 1) {
            up += __shfl_xor(up, m);
            bp += __shfl_xor(bp, m);
        }
        if (lane == 0) { redU[w] = up; redB[w] = bp; }
    }
    __syncthreads();

    const int um = 16 * w + c16;           // owned u (x4 duplicated across g4)

    // pot prefetch registers, rows 1..4
    float pv0 = potb[(size_t)1 * Uc + um];
    float pv1 = potb[(size_t)2 * Uc + um];
    float pv2 = potb[(size_t)3 * Uc + um];
    float pv3 = potb[(size_t)4 * Uc + um];

    // ---- init (t = 0): er = exp(pot0)*r, M = -ln(r), r = rcp(gmax) ----
    float er = __builtin_exp2f(potb[um] * LOG2E);
    float M;
    {
        float m = er;                      // max over the 16-lane group
        m = fmaxf(m, __shfl_xor(m, 1));
        m = fmaxf(m, __shfl_xor(m, 2));
        m = fmaxf(m, __shfl_xor(m, 4));
        m = fmaxf(m, __shfl_xor(m, 8));
        if (lane == 0) wred[w] = m;
        __syncthreads();
        f32x4 q0 = *(const f32x4*)&wred[0];
        f32x4 q1 = *(const f32x4*)&wred[4];
        f32x4 q2 = *(const f32x4*)&wred[8];
        f32x4 q3 = *(const f32x4*)&wred[12];
        float g = fmaxf(
            fmaxf(fmaxf(fmaxf(q0[0], q0[1]), fmaxf(q0[2], q0[3])),
                  fmaxf(fmaxf(q1[0], q1[1]), fmaxf(q1[2], q1[3]))),
            fmaxf(fmaxf(fmaxf(q2[0], q2[1]), fmaxf(q2[2], q2[3])),
                  fmaxf(fmaxf(q3[0], q3[1]), fmaxf(q3[2], q3[3]))));
        const float r = __builtin_amdgcn_rcpf(g);
        M  = -LN2 * __builtin_log2f(r);    // exact log of applied scale
        er = er * r;
        if (lane < 16) ea_lds[0][um] = (__bf16)er;
        if (lane == 0) mx[1][w] = m * r;   // post-scale wave max, slot 1
        __syncthreads();
    }

    // One step. Reads ea_lds[RP], writes ea_lds[WP]. CHK: deferred rescale
    // path (fires when TT%8==0; uses wave-maxes written 8 steps earlier).
    #define STEPX(TT, PVC, RP, WP, CHK)                                        \
    {                                                                          \
        bf16x8 af[8];                                                          \
        const __bf16* ebase = &ea_lds[(RP)][8 * g4];                           \
        _Pragma("unroll")                                                      \
        for (int kt = 0; kt < 8; ++kt)                                         \
            af[kt] = *(const bf16x8*)(ebase + 32 * kt);                        \
        float pef = __builtin_exp2f((PVC) * LOG2E - CC2);                      \
        float dM = 0.0f;                                                       \
        const bool dor = (CHK) && (((TT) & 7) == 0);                           \
        if (dor) {                                                             \
            const int sl = ((TT) >> 3) & 1;                                    \
            f32x4 m0 = *(const f32x4*)&mx[sl][0];                              \
            f32x4 m1 = *(const f32x4*)&mx[sl][4];                              \
            f32x4 m2 = *(const f32x4*)&mx[sl][8];                              \
            f32x4 m3 = *(const f32x4*)&mx[sl][12];                             \
            float g = fmaxf(                                                   \
                fmaxf(fmaxf(fmaxf(m0[0], m0[1]), fmaxf(m0[2], m0[3])),         \
                      fmaxf(fmaxf(m1[0], m1[1]), fmaxf(m1[2], m1[3]))),        \
                fmaxf(fmaxf(fmaxf(m2[0], m2[1]), fmaxf(m2[2], m2[3])),         \
                      fmaxf(fmaxf(m3[0], m3[1]), fmaxf(m3[2], m3[3]))));       \
            const float r = __builtin_amdgcn_rcpf(g);                          \
            dM  = -LN2 * __builtin_log2f(r);                                   \
            pef *= r;                                                          \
        }                                                                      \
        const f32x4 z = {0.f, 0.f, 0.f, 0.f};                                  \
        f32x4 cl = z, ch = z;                                                  \
        _Pragma("unroll")                                                      \
        for (int kt = 0; kt < 4; ++kt)                                         \
            cl = __builtin_amdgcn_mfma_f32_16x16x32_bf16(af[kt], bfr[kt], cl, 0, 0, 0); \
        _Pragma("unroll")                                                      \
        for (int kt = 4; kt < 8; ++kt)                                         \
            ch = __builtin_amdgcn_mfma_f32_16x16x32_bf16(af[kt], bfr[kt], ch, 0, 0, 0); \
        er = (cl[0] + ch[0]) * pef;                                            \
        if (lane < 16) ea_lds[(WP)][um] = (__bf16)er;                          \
        if (dor) {                                                             \
            M += dM;                                                           \
            float m = er;                                                      \
            m = fmaxf(m, __shfl_xor(m, 1));                                    \
            m = fmaxf(m, __shfl_xor(m, 2));                                    \
            m = fmaxf(m, __shfl_xor(m, 4));                                    \
            m = fmaxf(m, __shfl_xor(m, 8));                                    \
            if (lane == 0) mx[(((TT) >> 3) & 1) ^ 1][w] = m;                   \
        }                                                                      \
        wg_barrier();                                                          \
    }

    // ---- main recursion: t = 1 .., x4 unroll, clamp-free prefetch ----
    // t stays ≡ 1 (mod 4): bodies 1-3 never hit TT%8==0 -> CHK=0.
    int t = 1;
    for (; t + 3 < L && t + 7 < Tc; t += 4) {
        {
            const float pvc = pv0;
            pv0 = potb[(size_t)(t + 4) * Uc + um];
            STEPX(t, pvc, (t + 1) & 1, t & 1, 0);
        }
        {
            const float pvc = pv1;
            pv1 = potb[(size_t)(t + 5) * Uc + um];
            STEPX(t + 1, pvc, t & 1, (t + 1) & 1, 0);
        }
        {
            const float pvc = pv2;
            pv2 = potb[(size_t)(t + 6) * Uc + um];
            STEPX(t + 2, pvc, (t + 1) & 1, t & 1, 0);
        }
        {
            const float pvc = pv3;
            pv3 = potb[(size_t)(t + 7) * Uc + um];
            STEPX(t + 3, pvc, t & 1, (t + 1) & 1, 1);
        }
    }
    // ---- tail: first 4 steps reuse still-valid prefetches ----
    if (t < L) { STEPX(t, pv0, (t + 1) & 1, t & 1, 1); ++t; }
    if (t < L) { STEPX(t, pv1, (t + 1) & 1, t & 1, 1); ++t; }
    if (t < L) { STEPX(t, pv2, (t + 1) & 1, t & 1, 1); ++t; }
    if (t < L) { STEPX(t, pv3, (t + 1) & 1, t & 1, 1); ++t; }
    for (; t < L; ++t) {
        const float pvc = potb[(size_t)t * Uc + um];
        STEPX(t, pvc, (t + 1) & 1, t & 1, 1);
    }

    // ---- epilogue: logZ = M + (L-1)*c + ln(sum er);  ll = U + B - logZ ----
    {
        float ssum = er;                   // sum over 16 distinct lanes
        ssum += __shfl_xor(ssum, 1);
        ssum += __shfl_xor(ssum, 2);
        ssum += __shfl_xor(ssum, 4);
        ssum += __shfl_xor(ssum, 8);
        if (lane == 0) wred[w] = ssum;
        __syncthreads();
        if (tid == 0) {
            float S = 0.f, uS = 0.f, bS = 0.f;
            #pragma unroll
            for (int i = 0; i < NW; ++i) { S += wred[i]; uS += redU[i]; bS += redB[i]; }
            const float cstep = CC2 * LN2;           // = 5.0 nats per step
            const float logZ = M + (float)(L - 1) * cstep
                             + LN2 * __builtin_log2f(S);
            ws[b] = uS + bS - logZ;
            __threadfence();
            // d_ws re-poisoned to 0xAA before every launch (harness contract,
            // verified passing in rounds 3/4) -> counter starts 0xAAAAAAAA.
            unsigned old = atomicAdd((unsigned*)(ws + Bc), 1u);
            if (old == 0xAAAAAAAAu + (unsigned)(Bc - 1)) {
                __threadfence();
                float S2 = 0.f;
                #pragma unroll
                for (int i = 0; i < Bc; ++i) S2 += ws[i];
                out[0] = -S2 * (1.0f / (float)Bc);
            }
        }
    }
    #undef STEPX
}

extern "C" void kernel_launch(void* const* d_in, const int* in_sizes, int n_in,
                              void* d_out, int out_size, void* d_ws, size_t ws_size,
                              hipStream_t stream) {
    const float* pot   = (const float*)d_in[0];
    const int*   tags  = (const int*)d_in[1];
    const int*   slen  = (const int*)d_in[2];
    const float* trans = (const float*)d_in[3];
    float* wsf = (float*)d_ws;
    float* out = (float*)d_out;

    crf_fwd<<<Bc, 64 * NW, 0, stream>>>(pot, tags, slen, trans, wsf, out);
}

// Round 6
// 307.548 us; speedup vs baseline: 1.0281x; 1.0281x over previous
//
#include <hip/hip_runtime.h>

// CRF negative mean log-likelihood, B=64, T=512, U=256.
//
// Round 6: r5's 16-wave (4 waves/SIMD) design, de-spilled.
// r5 failed because __launch_bounds__(1024,1) let the allocator target
// 2 blocks/CU -> 64 VGPRs -> spills (WRITE_SIZE 11.9MB, 30ms outlier).
// Fix: __launch_bounds__(1024,4) -> 1 block/CU -> 128 VGPR cap (need ~100).
// Also: 4 accumulator chains of depth 2 (was 2x depth-4) to cut ~2 MFMA
// latencies off the per-step serial chain.
// Keeps: deferred stale rescale (no 2nd barrier), CC2 normalizer folded in
// exp2, clamp-free x4-unrolled prefetch, fused final mean via ws-counter.

#define Bc 64
#define Tc 512
#define Uc 256
#define NW 16                  // waves per block
#define LOG2E 1.4426950408889634f
#define LN2   0.6931471805599453f
#define CC2   7.2134752f       // per-step normalizer in log2 domain (= 5 nats)

typedef __bf16 bf16x8 __attribute__((ext_vector_type(8)));
typedef float  f32x4  __attribute__((ext_vector_type(4)));

// Raw barrier: does NOT drain vmcnt (pot prefetches stay in flight).
__device__ __forceinline__ void wg_barrier() {
    asm volatile("s_waitcnt lgkmcnt(0)" ::: "memory");
    __builtin_amdgcn_s_barrier();
    asm volatile("" ::: "memory");
}

__global__ __launch_bounds__(1024, 4)   // 4 waves/EU min -> 1 block/CU -> 128 VGPRs
void crf_fwd(const float* __restrict__ pot, const int* __restrict__ tags,
             const int* __restrict__ seqlen, const float* __restrict__ trans,
             float* __restrict__ ws, float* __restrict__ out)
{
    const int b    = blockIdx.x;
    const int tid  = threadIdx.x;          // 0..1023
    const int lane = tid & 63;
    const int w    = tid >> 6;             // wave 0..15
    const int g4   = lane >> 4;            // k-group 0..3
    const int c16  = lane & 15;            // fragment column
    const int L    = seqlen[b];

    __shared__ __align__(16) __bf16 ea_lds[2][Uc];
    __shared__ __align__(16) float mx[2][NW];  // double-buffered wave maxes
    __shared__ float wred[NW];
    __shared__ float redU[NW], redB[NW];

    const float* potb = pot  + (size_t)b * Tc * Uc;
    const int*   tagb = tags + b * Tc;

    // ---- B fragments: E = exp(trans), bf16, registers ----
    // wave w owns ONE n-tile: u in [16w, 16w+16).
    // elem e of lane l = E[v = 32kt + 8g4 + e][u = 16w + c16].
    // Same (lane,e)->k placement as A fragments (k-permutation cancels;
    // validated absmax 0.0 in rounds 1/3/4/5).
    bf16x8 bfr[8];
    #pragma unroll
    for (int kt = 0; kt < 8; ++kt) {
        const int u = 16 * w + c16;
        bf16x8 bb;
        #pragma unroll
        for (int e = 0; e < 8; ++e) {
            const int v = 32 * kt + 8 * g4 + e;
            bb[e] = (__bf16)__builtin_exp2f(trans[v * Uc + u] * LOG2E);
        }
        bfr[kt] = bb;
    }

    // ---- prologue: unary + binary scores, block-parallel over t ----
    {
        const int t  = tid;                // 0..1023; only t < L contribute
        float up = 0.f, bp = 0.f;
        if (t < L) {
            const int tg = tagb[t];
            up = potb[(size_t)t * Uc + tg];
            if (t >= 1) bp = trans[tagb[t - 1] * Uc + tg];
        }
        #pragma unroll
        for (int m = 1; m < 64; m <<= 1) {
            up += __shfl_xor(up, m);
            bp += __shfl_xor(bp, m);
        }
        if (lane == 0) { redU[w] = up; redB[w] = bp; }
    }
    __syncthreads();

    const int um = 16 * w + c16;           // owned u (x4 duplicated across g4)

    // pot prefetch registers, rows 1..4
    float pv0 = potb[(size_t)1 * Uc + um];
    float pv1 = potb[(size_t)2 * Uc + um];
    float pv2 = potb[(size_t)3 * Uc + um];
    float pv3 = potb[(size_t)4 * Uc + um];

    // ---- init (t = 0): er = exp(pot0)*r, M = -ln(r), r = rcp(gmax) ----
    float er = __builtin_exp2f(potb[um] * LOG2E);
    float M;
    {
        float m = er;                      // max over the 16-lane group
        m = fmaxf(m, __shfl_xor(m, 1));
        m = fmaxf(m, __shfl_xor(m, 2));
        m = fmaxf(m, __shfl_xor(m, 4));
        m = fmaxf(m, __shfl_xor(m, 8));
        if (lane == 0) wred[w] = m;
        __syncthreads();
        f32x4 q0 = *(const f32x4*)&wred[0];
        f32x4 q1 = *(const f32x4*)&wred[4];
        f32x4 q2 = *(const f32x4*)&wred[8];
        f32x4 q3 = *(const f32x4*)&wred[12];
        float g = fmaxf(
            fmaxf(fmaxf(fmaxf(q0[0], q0[1]), fmaxf(q0[2], q0[3])),
                  fmaxf(fmaxf(q1[0], q1[1]), fmaxf(q1[2], q1[3]))),
            fmaxf(fmaxf(fmaxf(q2[0], q2[1]), fmaxf(q2[2], q2[3])),
                  fmaxf(fmaxf(q3[0], q3[1]), fmaxf(q3[2], q3[3]))));
        const float r = __builtin_amdgcn_rcpf(g);
        M  = -LN2 * __builtin_log2f(r);    // exact log of applied scale
        er = er * r;
        if (lane < 16) ea_lds[0][um] = (__bf16)er;
        if (lane == 0) mx[1][w] = m * r;   // post-scale wave max, slot 1
        __syncthreads();
    }

    // One step. Reads ea_lds[RP], writes ea_lds[WP]. CHK: deferred rescale
    // path (fires when TT%8==0; uses wave-maxes written 8 steps earlier).
    // 4 accumulator chains of depth 2 -> shorter serial MFMA tail.
    #define STEPX(TT, PVC, RP, WP, CHK)                                        \
    {                                                                          \
        bf16x8 af[8];                                                          \
        const __bf16* ebase = &ea_lds[(RP)][8 * g4];                           \
        _Pragma("unroll")                                                      \
        for (int kt = 0; kt < 8; ++kt)                                         \
            af[kt] = *(const bf16x8*)(ebase + 32 * kt);                        \
        float pef = __builtin_exp2f((PVC) * LOG2E - CC2);                      \
        float dM = 0.0f;                                                       \
        const bool dor = (CHK) && (((TT) & 7) == 0);                           \
        if (dor) {                                                             \
            const int sl = ((TT) >> 3) & 1;                                    \
            f32x4 m0 = *(const f32x4*)&mx[sl][0];                              \
            f32x4 m1 = *(const f32x4*)&mx[sl][4];                              \
            f32x4 m2 = *(const f32x4*)&mx[sl][8];                              \
            f32x4 m3 = *(const f32x4*)&mx[sl][12];                             \
            float g = fmaxf(                                                   \
                fmaxf(fmaxf(fmaxf(m0[0], m0[1]), fmaxf(m0[2], m0[3])),         \
                      fmaxf(fmaxf(m1[0], m1[1]), fmaxf(m1[2], m1[3]))),        \
                fmaxf(fmaxf(fmaxf(m2[0], m2[1]), fmaxf(m2[2], m2[3])),         \
                      fmaxf(fmaxf(m3[0], m3[1]), fmaxf(m3[2], m3[3]))));       \
            const float r = __builtin_amdgcn_rcpf(g);                          \
            dM  = -LN2 * __builtin_log2f(r);                                   \
            pef *= r;                                                          \
        }                                                                      \
        const f32x4 z = {0.f, 0.f, 0.f, 0.f};                                  \
        f32x4 c0 = z, c1 = z, c2 = z, c3 = z;                                  \
        c0 = __builtin_amdgcn_mfma_f32_16x16x32_bf16(af[0], bfr[0], c0, 0, 0, 0); \
        c1 = __builtin_amdgcn_mfma_f32_16x16x32_bf16(af[2], bfr[2], c1, 0, 0, 0); \
        c2 = __builtin_amdgcn_mfma_f32_16x16x32_bf16(af[4], bfr[4], c2, 0, 0, 0); \
        c3 = __builtin_amdgcn_mfma_f32_16x16x32_bf16(af[6], bfr[6], c3, 0, 0, 0); \
        c0 = __builtin_amdgcn_mfma_f32_16x16x32_bf16(af[1], bfr[1], c0, 0, 0, 0); \
        c1 = __builtin_amdgcn_mfma_f32_16x16x32_bf16(af[3], bfr[3], c1, 0, 0, 0); \
        c2 = __builtin_amdgcn_mfma_f32_16x16x32_bf16(af[5], bfr[5], c2, 0, 0, 0); \
        c3 = __builtin_amdgcn_mfma_f32_16x16x32_bf16(af[7], bfr[7], c3, 0, 0, 0); \
        er = ((c0[0] + c1[0]) + (c2[0] + c3[0])) * pef;                        \
        if (lane < 16) ea_lds[(WP)][um] = (__bf16)er;                          \
        if (dor) {                                                             \
            M += dM;                                                           \
            float m = er;                                                      \
            m = fmaxf(m, __shfl_xor(m, 1));                                    \
            m = fmaxf(m, __shfl_xor(m, 2));                                    \
            m = fmaxf(m, __shfl_xor(m, 4));                                    \
            m = fmaxf(m, __shfl_xor(m, 8));                                    \
            if (lane == 0) mx[(((TT) >> 3) & 1) ^ 1][w] = m;                   \
        }                                                                      \
        wg_barrier();                                                          \
    }

    // ---- main recursion: t = 1 .., x4 unroll, clamp-free prefetch ----
    // t stays ≡ 1 (mod 4): bodies 1-3 never hit TT%8==0 -> CHK=0.
    int t = 1;
    for (; t + 3 < L && t + 7 < Tc; t += 4) {
        {
            const float pvc = pv0;
            pv0 = potb[(size_t)(t + 4) * Uc + um];
            STEPX(t, pvc, (t + 1) & 1, t & 1, 0);
        }
        {
            const float pvc = pv1;
            pv1 = potb[(size_t)(t + 5) * Uc + um];
            STEPX(t + 1, pvc, t & 1, (t + 1) & 1, 0);
        }
        {
            const float pvc = pv2;
            pv2 = potb[(size_t)(t + 6) * Uc + um];
            STEPX(t + 2, pvc, (t + 1) & 1, t & 1, 0);
        }
        {
            const float pvc = pv3;
            pv3 = potb[(size_t)(t + 7) * Uc + um];
            STEPX(t + 3, pvc, t & 1, (t + 1) & 1, 1);
        }
    }
    // ---- tail: first 4 steps reuse still-valid prefetches ----
    if (t < L) { STEPX(t, pv0, (t + 1) & 1, t & 1, 1); ++t; }
    if (t < L) { STEPX(t, pv1, (t + 1) & 1, t & 1, 1); ++t; }
    if (t < L) { STEPX(t, pv2, (t + 1) & 1, t & 1, 1); ++t; }
    if (t < L) { STEPX(t, pv3, (t + 1) & 1, t & 1, 1); ++t; }
    for (; t < L; ++t) {
        const float pvc = potb[(size_t)t * Uc + um];
        STEPX(t, pvc, (t + 1) & 1, t & 1, 1);
    }

    // ---- epilogue: logZ = M + (L-1)*c + ln(sum er);  ll = U + B - logZ ----
    {
        float ssum = er;                   // sum over 16 distinct lanes
        ssum += __shfl_xor(ssum, 1);
        ssum += __shfl_xor(ssum, 2);
        ssum += __shfl_xor(ssum, 4);
        ssum += __shfl_xor(ssum, 8);
        if (lane == 0) wred[w] = ssum;
        __syncthreads();
        if (tid == 0) {
            float S = 0.f, uS = 0.f, bS = 0.f;
            #pragma unroll
            for (int i = 0; i < NW; ++i) { S += wred[i]; uS += redU[i]; bS += redB[i]; }
            const float cstep = CC2 * LN2;           // = 5.0 nats per step
            const float logZ = M + (float)(L - 1) * cstep
                             + LN2 * __builtin_log2f(S);
            ws[b] = uS + bS - logZ;
            __threadfence();
            // d_ws re-poisoned to 0xAA before every launch (harness contract,
            // verified across graph replays in rounds 3/4/5) -> counter
            // starts at 0xAAAAAAAA.
            unsigned old = atomicAdd((unsigned*)(ws + Bc), 1u);
            if (old == 0xAAAAAAAAu + (unsigned)(Bc - 1)) {
                __threadfence();
                float S2 = 0.f;
                #pragma unroll
                for (int i = 0; i < Bc; ++i) S2 += ws[i];
                out[0] = -S2 * (1.0f / (float)Bc);
            }
        }
    }
    #undef STEPX
}

extern "C" void kernel_launch(void* const* d_in, const int* in_sizes, int n_in,
                              void* d_out, int out_size, void* d_ws, size_t ws_size,
                              hipStream_t stream) {
    const float* pot   = (const float*)d_in[0];
    const int*   tags  = (const int*)d_in[1];
    const int*   slen  = (const int*)d_in[2];
    const float* trans = (const float*)d_in[3];
    float* wsf = (float*)d_ws;
    float* out = (float*)d_out;

    crf_fwd<<<Bc, 64 * NW, 0, stream>>>(pot, tags, slen, trans, wsf, out);
}